// Round 16
// baseline (487.237 us; speedup 1.0000x reference)
//
#include <hip/hip_runtime.h>

#define LRELU(v) ((v) > 0.0f ? (v) : 0.01f * (v))

__device__ __forceinline__ unsigned short f2bf(float f) {
    union { float f; unsigned u; } c;
    c.f = f;
    return (unsigned short)((c.u + 0x7fffu + ((c.u >> 16) & 1)) >> 16);
}
__device__ __forceinline__ float bf_lo(unsigned u) {
    union { unsigned i; float f; } v;
    v.i = u << 16;
    return v.f;
}
__device__ __forceinline__ float bf_hi(unsigned u) {
    union { unsigned i; float f; } v;
    v.i = u & 0xffff0000u;
    return v.f;
}

// ================= two-level bucket CSR build ================================
__global__ void bucket_count_k(const int* __restrict__ col, int* __restrict__ bcnt, int E) {
    __shared__ int lcnt[512];
    int tid = threadIdx.x;  // 1024
    for (int i = tid; i < 512; i += 1024) lcnt[i] = 0;
    __syncthreads();
    int base = blockIdx.x * 8192;
    for (int k = 0; k < 8; ++k) {
        int e = base + k * 1024 + tid;
        if (e < E) atomicAdd(&lcnt[col[e] >> 7], 1);
    }
    __syncthreads();
    for (int i = tid; i < 512; i += 1024) {
        int v = lcnt[i];
        if (v) atomicAdd(&bcnt[i], v);
    }
}

__global__ void bucket_scan_k(const int* __restrict__ bcnt, int* __restrict__ bbase,
                              int* __restrict__ bwp, int NBUCK, int E) {
    __shared__ int s[512];
    int tid = threadIdx.x;  // 512
    int v = (tid < NBUCK) ? bcnt[tid] : 0;
    s[tid] = v;
    __syncthreads();
    for (int off = 1; off < 512; off <<= 1) {
        int t = (tid >= off) ? s[tid - off] : 0;
        __syncthreads();
        s[tid] += t;
        __syncthreads();
    }
    if (tid < NBUCK) {
        int ex = s[tid] - v;
        bbase[tid] = ex;
        bwp[tid] = ex;
    }
    if (tid == 0) bbase[NBUCK] = E;
}

__global__ void bucket_scatter_k(const int* __restrict__ row, const int* __restrict__ col,
                                 int* __restrict__ bwp, int2* __restrict__ tmp, int E) {
    __shared__ int lcnt[512];
    __shared__ int gbase[512];
    int tid = threadIdx.x;  // 1024
    for (int i = tid; i < 512; i += 1024) lcnt[i] = 0;
    __syncthreads();
    int base = blockIdx.x * 8192;
    int lpos[8], bk[8];
    for (int k = 0; k < 8; ++k) {
        int e = base + k * 1024 + tid;
        if (e < E) {
            int b = col[e] >> 7;
            bk[k] = b;
            lpos[k] = atomicAdd(&lcnt[b], 1);
        } else
            bk[k] = -1;
    }
    __syncthreads();
    for (int i = tid; i < 512; i += 1024) {
        int v = lcnt[i];
        gbase[i] = v ? atomicAdd(&bwp[i], v) : 0;
    }
    __syncthreads();
    for (int k = 0; k < 8; ++k) {
        int e = base + k * 1024 + tid;
        if (e < E) {
            int c = col[e];
            tmp[gbase[bk[k]] + lpos[k]] = make_int2(row[e], ((c & 127) << 25) | e);
        }
    }
}

__global__ void bucket_csr_k(const int2* __restrict__ tmp, const int* __restrict__ bbase,
                             int* __restrict__ rowptr, int* __restrict__ cnt,
                             int2* __restrict__ pairs, int N, int E) {
    constexpr int CAP = 6144;
    __shared__ int2 buf[CAP];
    __shared__ int lcnt[128];
    __shared__ int sscan[128];
    __shared__ int lwp[128];
    int b = blockIdx.x;
    int tid = threadIdx.x;  // 256
    int s = bbase[b], e = bbase[b + 1];
    int sz = e - s;
    if (tid < 128) lcnt[tid] = 0;
    __syncthreads();
    for (int i = tid; i < sz; i += 256) {
        int2 v = tmp[s + i];
        if (i < CAP) buf[i] = v;
        atomicAdd(&lcnt[((unsigned)v.y) >> 25], 1);
    }
    __syncthreads();
    if (tid < 128) sscan[tid] = lcnt[tid];
    __syncthreads();
    for (int off = 1; off < 128; off <<= 1) {
        int t = (tid < 128 && tid >= off) ? sscan[tid - off] : 0;
        __syncthreads();
        if (tid < 128) sscan[tid] += t;
        __syncthreads();
    }
    if (tid < 128) {
        int ex = sscan[tid] - lcnt[tid];
        lwp[tid] = ex;
        int c = b * 128 + tid;
        if (c < N) {
            rowptr[c] = s + ex;
            cnt[c] = lcnt[tid];
            if (c == N - 1) rowptr[N] = E;
        }
    }
    __syncthreads();
    for (int i = tid; i < sz; i += 256) {
        int2 v = (i < CAP) ? buf[i] : tmp[s + i];
        int cl = ((unsigned)v.y) >> 25;
        int p = atomicAdd(&lwp[cl], 1);
        pairs[s + p] = make_int2(v.x, v.y & 0x1FFFFFF);
    }
}

// ---------------- dual GEMM: hl = h@wl (bf16), hr = h@wr + bl ----------------
template <int FIN, int FOUT, bool BFL>
__global__ void gemm2_k(const float* __restrict__ h, const float* __restrict__ wl,
                        const float* __restrict__ wr, const float* __restrict__ bl,
                        void* __restrict__ hl, float* __restrict__ hr, int N) {
    constexpr int XT = (2 * FOUT) / 4;
    constexpr int YT = 256 / XT;
    constexpr int NPT = 4;
    constexpr int NPB = YT * NPT;
    __shared__ float sw[FIN * 2 * FOUT];
    int lin = threadIdx.y * XT + threadIdx.x;
    for (int idx = lin; idx < FIN * FOUT; idx += 256) {
        int f = idx / FOUT, o = idx % FOUT;
        sw[f * 2 * FOUT + o] = wl[idx];
        sw[f * 2 * FOUT + FOUT + o] = wr[idx];
    }
    __syncthreads();
    int og = threadIdx.x * 4;
    int base = blockIdx.x * NPB + threadIdx.y * NPT;
    int ix[NPT] = {min(base + 0, N - 1), min(base + 1, N - 1), min(base + 2, N - 1),
                   min(base + 3, N - 1)};
    float4 s[NPT] = {{0.f, 0.f, 0.f, 0.f}, {0.f, 0.f, 0.f, 0.f}, {0.f, 0.f, 0.f, 0.f},
                     {0.f, 0.f, 0.f, 0.f}};
#pragma unroll 2
    for (int f = 0; f < FIN; f += 4) {
        float4 w0 = *(const float4*)&sw[(f + 0) * 2 * FOUT + og];
        float4 w1 = *(const float4*)&sw[(f + 1) * 2 * FOUT + og];
        float4 w2 = *(const float4*)&sw[(f + 2) * 2 * FOUT + og];
        float4 w3 = *(const float4*)&sw[(f + 3) * 2 * FOUT + og];
#pragma unroll
        for (int k = 0; k < NPT; ++k) {
            float4 v = *(const float4*)(h + (size_t)ix[k] * FIN + f);
            s[k].x += v.x * w0.x + v.y * w1.x + v.z * w2.x + v.w * w3.x;
            s[k].y += v.x * w0.y + v.y * w1.y + v.z * w2.y + v.w * w3.y;
            s[k].z += v.x * w0.z + v.y * w1.z + v.z * w2.z + v.w * w3.z;
            s[k].w += v.x * w0.w + v.y * w1.w + v.z * w2.w + v.w * w3.w;
        }
    }
    bool isR = og >= FOUT;
    int oo = isR ? og - FOUT : og;
    if (isR) {
        float4 bias = *(const float4*)&bl[oo];
#pragma unroll
        for (int k = 0; k < NPT; ++k) {
            int i = base + k;
            if (i < N) {
                float4 r = {s[k].x + bias.x, s[k].y + bias.y, s[k].z + bias.z, s[k].w + bias.w};
                *(float4*)(hr + (size_t)i * FOUT + oo) = r;
            }
        }
    } else {
#pragma unroll
        for (int k = 0; k < NPT; ++k) {
            int i = base + k;
            if (i < N) {
                if (BFL) {
                    unsigned short* d = (unsigned short*)hl + (size_t)i * FOUT + oo;
                    *(ushort4*)d =
                        make_ushort4(f2bf(s[k].x), f2bf(s[k].y), f2bf(s[k].z), f2bf(s[k].w));
                } else {
                    *(float4*)((float*)hl + (size_t)i * FOUT + oo) = s[k];
                }
            }
        }
    }
}

// ---------------- fused SAGE aggregate+epilogue, 64-wide, bf16 table ---------
// wave = 4 rows x 16 lanes; unroll 4 (mean degree 16 => one iteration).
__global__ void aggr_fused64_bf_k(const unsigned short* __restrict__ hlb,
                                  const float* __restrict__ hr, const int* __restrict__ rowptr,
                                  const int2* __restrict__ pairs, float* __restrict__ out, int N) {
    int wave = (blockIdx.x * blockDim.x + threadIdx.x) >> 6;
    int lane = threadIdx.x & 63;
    if (wave >= N) return;
    int u = lane >> 4, f4 = lane & 15;
    int s = rowptr[wave], e = rowptr[wave + 1];
    float4 a = {0.f, 0.f, 0.f, 0.f};
    int p = s + u;
    for (; p + 12 < e; p += 16) {
        int r0 = pairs[p].x, r1 = pairs[p + 4].x, r2 = pairs[p + 8].x, r3 = pairs[p + 12].x;
        uint2 v0 = ((const uint2*)(hlb + (size_t)r0 * 64))[f4];
        uint2 v1 = ((const uint2*)(hlb + (size_t)r1 * 64))[f4];
        uint2 v2 = ((const uint2*)(hlb + (size_t)r2 * 64))[f4];
        uint2 v3 = ((const uint2*)(hlb + (size_t)r3 * 64))[f4];
        a.x += (bf_lo(v0.x) + bf_lo(v1.x)) + (bf_lo(v2.x) + bf_lo(v3.x));
        a.y += (bf_hi(v0.x) + bf_hi(v1.x)) + (bf_hi(v2.x) + bf_hi(v3.x));
        a.z += (bf_lo(v0.y) + bf_lo(v1.y)) + (bf_lo(v2.y) + bf_lo(v3.y));
        a.w += (bf_hi(v0.y) + bf_hi(v1.y)) + (bf_hi(v2.y) + bf_hi(v3.y));
    }
    for (; p + 4 < e; p += 8) {
        int r0 = pairs[p].x, r1 = pairs[p + 4].x;
        uint2 v0 = ((const uint2*)(hlb + (size_t)r0 * 64))[f4];
        uint2 v1 = ((const uint2*)(hlb + (size_t)r1 * 64))[f4];
        a.x += bf_lo(v0.x) + bf_lo(v1.x);
        a.y += bf_hi(v0.x) + bf_hi(v1.x);
        a.z += bf_lo(v0.y) + bf_lo(v1.y);
        a.w += bf_hi(v0.y) + bf_hi(v1.y);
    }
    if (p < e) {
        uint2 v = ((const uint2*)(hlb + (size_t)pairs[p].x * 64))[f4];
        a.x += bf_lo(v.x); a.y += bf_hi(v.x); a.z += bf_lo(v.y); a.w += bf_hi(v.y);
    }
    a.x += __shfl_down(a.x, 32); a.y += __shfl_down(a.y, 32);
    a.z += __shfl_down(a.z, 32); a.w += __shfl_down(a.w, 32);
    a.x += __shfl_down(a.x, 16); a.y += __shfl_down(a.y, 16);
    a.z += __shfl_down(a.z, 16); a.w += __shfl_down(a.w, 16);
    if (lane < 16) {
        float inv = 1.0f / fmaxf((float)(e - s), 1.0f);
        float4 r = ((const float4*)(hr + (size_t)wave * 64))[f4];
        float4 o;
        o.x = LRELU(a.x * inv + r.x);
        o.y = LRELU(a.y * inv + r.y);
        o.z = LRELU(a.z * inv + r.z);
        o.w = LRELU(a.w * inv + r.w);
        ((float4*)(out + (size_t)wave * 64))[f4] = o;
    }
}

// ---------------- fused SAGE aggregate+epilogue, 32-wide, bf16 table ---------
// wave = 8 rows x 8 lanes; unroll 2 (degree 16 => one iteration).
template <bool OUTBF>
__global__ void aggr_fused32_bf_k(const unsigned short* __restrict__ hlb,
                                  const float* __restrict__ hr, const int* __restrict__ rowptr,
                                  const int2* __restrict__ pairs, void* __restrict__ out, int N) {
    int wave = (blockIdx.x * blockDim.x + threadIdx.x) >> 6;
    int lane = threadIdx.x & 63;
    if (wave >= N) return;
    int u = lane >> 3, f4 = lane & 7;
    int s = rowptr[wave], e = rowptr[wave + 1];
    float4 a = {0.f, 0.f, 0.f, 0.f};
    int p = s + u;
    for (; p + 8 < e; p += 16) {
        int r0 = pairs[p].x, r1 = pairs[p + 8].x;
        uint2 v0 = ((const uint2*)(hlb + (size_t)r0 * 32))[f4];
        uint2 v1 = ((const uint2*)(hlb + (size_t)r1 * 32))[f4];
        a.x += bf_lo(v0.x) + bf_lo(v1.x);
        a.y += bf_hi(v0.x) + bf_hi(v1.x);
        a.z += bf_lo(v0.y) + bf_lo(v1.y);
        a.w += bf_hi(v0.y) + bf_hi(v1.y);
    }
    if (p < e) {
        uint2 v = ((const uint2*)(hlb + (size_t)pairs[p].x * 32))[f4];
        a.x += bf_lo(v.x); a.y += bf_hi(v.x); a.z += bf_lo(v.y); a.w += bf_hi(v.y);
    }
    a.x += __shfl_down(a.x, 32); a.y += __shfl_down(a.y, 32);
    a.z += __shfl_down(a.z, 32); a.w += __shfl_down(a.w, 32);
    a.x += __shfl_down(a.x, 16); a.y += __shfl_down(a.y, 16);
    a.z += __shfl_down(a.z, 16); a.w += __shfl_down(a.w, 16);
    a.x += __shfl_down(a.x, 8); a.y += __shfl_down(a.y, 8);
    a.z += __shfl_down(a.z, 8); a.w += __shfl_down(a.w, 8);
    if (lane < 8) {
        float inv = 1.0f / fmaxf((float)(e - s), 1.0f);
        const float4* hp = (const float4*)(hr + (size_t)wave * 32);
        float4 r = hp[f4];
        float4 o;
        o.x = LRELU(a.x * inv + r.x);
        o.y = LRELU(a.y * inv + r.y);
        o.z = LRELU(a.z * inv + r.z);
        o.w = LRELU(a.w * inv + r.w);
        if (OUTBF) {
            unsigned short* d = (unsigned short*)out + (size_t)wave * 32 + f4 * 4;
            *(ushort4*)d = make_ushort4(f2bf(o.x), f2bf(o.y), f2bf(o.z), f2bf(o.w));
        } else {
            ((float4*)((float*)out + (size_t)wave * 32))[f4] = o;
        }
    }
}

// ---------------- edge conv layer 0: wave = 32 neighbors x 2 f4-lanes --------
__global__ void edge_aggr8_k(const float* __restrict__ dis, const int* __restrict__ rowptr,
                             const int2* __restrict__ pairs, float* __restrict__ sd, int N) {
    int wave = (blockIdx.x * blockDim.x + threadIdx.x) >> 6;
    int lane = threadIdx.x & 63;
    if (wave >= N) return;
    int u = lane >> 1, f4 = lane & 1;
    int s = rowptr[wave], e = rowptr[wave + 1];
    float4 a = {0.f, 0.f, 0.f, 0.f};
    for (int p = s + u; p < e; p += 32) {
        const float4* dp = (const float4*)(dis + (size_t)pairs[p].y * 8);
        float4 v = dp[f4];
        a.x += v.x; a.y += v.y; a.z += v.z; a.w += v.w;
    }
    for (int off = 32; off >= 2; off >>= 1) {
        a.x += __shfl_down(a.x, off); a.y += __shfl_down(a.y, off);
        a.z += __shfl_down(a.z, off); a.w += __shfl_down(a.w, off);
    }
    if (lane < 2) ((float4*)(sd + (size_t)wave * 8))[f4] = a;
}

// ---------------- all four W12 = w1 @ w2 in one launch (templated bodies) ----
template <int H2, int HOUT>
__device__ __forceinline__ void w12_body(const float* __restrict__ w1,
                                         const float* __restrict__ w2, float* __restrict__ out,
                                         int i, int o) {
    float s = 0.0f;
#pragma unroll
    for (int k = 0; k < H2; ++k) s += w1[i * H2 + k] * w2[k * HOUT + o];
    out[i * HOUT + o] = s;
}

__global__ void gemm_w12_all_k(const float* __restrict__ w1_0, const float* __restrict__ w2_0,
                               float* __restrict__ o0, const float* __restrict__ w1_1,
                               const float* __restrict__ w2_1, float* __restrict__ o1,
                               const float* __restrict__ w1_2, const float* __restrict__ w2_2,
                               float* __restrict__ o2, const float* __restrict__ w1_3,
                               const float* __restrict__ w2_3, float* __restrict__ o3) {
    int b = blockIdx.x;
    int o = threadIdx.x;
    if (b < 8) {
        w12_body<128, 64>(w1_0, w2_0, o0, b, o);
    } else if (b < 72) {
        w12_body<128, 64>(w1_1, w2_1, o1, b - 8, o);
    } else if (b < 136) {
        if (o < 32) w12_body<64, 32>(w1_2, w2_2, o2, b - 72, o);
    } else {
        if (o < 32) w12_body<64, 32>(w1_3, w2_3, o3, b - 136, o);
    }
}

// ---------------- collapsed edge conv + fused next-layer delta scatter -------
template <int FIN, int FOUT>
__global__ void edge_compute_scatter_k(const float* __restrict__ sd, const int* __restrict__ cnt,
                                       const float* __restrict__ w12, const float* __restrict__ mw2,
                                       const float* __restrict__ b1w2, const float* __restrict__ b2,
                                       const float* __restrict__ cnext,
                                       const int* __restrict__ col, float* __restrict__ sdnext,
                                       int N) {
    constexpr int ROWS = 256 / FOUT;
    constexpr int NPT = 4;
    constexpr int NPB = ROWS * NPT;
    __shared__ float sw[FIN * FOUT];
    int lin = threadIdx.y * FOUT + threadIdx.x;
    for (int idx = lin; idx < FIN * FOUT; idx += 256) sw[idx] = w12[idx];
    __syncthreads();
    int o = threadIdx.x;
    int base = blockIdx.x * NPB + threadIdx.y * NPT;
    int ix[NPT] = {min(base + 0, N - 1), min(base + 1, N - 1), min(base + 2, N - 1),
                   min(base + 3, N - 1)};
    float s[NPT] = {0.f, 0.f, 0.f, 0.f};
#pragma unroll 2
    for (int f = 0; f < FIN; f += 4) {
        float w0 = sw[(f + 0) * FOUT + o], w1 = sw[(f + 1) * FOUT + o];
        float w2 = sw[(f + 2) * FOUT + o], w3 = sw[(f + 3) * FOUT + o];
#pragma unroll
        for (int k = 0; k < NPT; ++k) {
            float4 v = *(const float4*)(sd + (size_t)ix[k] * FIN + f);
            s[k] += v.x * w0 + v.y * w1 + v.z * w2 + v.w * w3;
        }
    }
    float mo = mw2[o], bo = b1w2[o], b2o = b2[o], co = cnext[o];
#pragma unroll
    for (int k = 0; k < NPT; ++k) {
        int i = base + k;
        if (i < N) {
            float deg = (float)cnt[i];
            float inv = 1.0f / (deg + 1.0f);
            float val = LRELU((s[k] + deg * mo + bo) * inv + b2o);
            atomicAdd(&sdnext[(size_t)col[i] * FOUT + o], val - co);
        }
    }
}

// ---------------- last edge conv: plain output write -------------------------
template <int FIN, int FOUT>
__global__ void edge_compute2_k(const float* __restrict__ sd, const int* __restrict__ cnt,
                                const float* __restrict__ w12, const float* __restrict__ mw2,
                                const float* __restrict__ b1w2, const float* __restrict__ b2,
                                float* __restrict__ out, int N) {
    constexpr int ROWS = 256 / FOUT;
    constexpr int NPT = 4;
    constexpr int NPB = ROWS * NPT;
    __shared__ float sw[FIN * FOUT];
    int lin = threadIdx.y * FOUT + threadIdx.x;
    for (int idx = lin; idx < FIN * FOUT; idx += 256) sw[idx] = w12[idx];
    __syncthreads();
    int o = threadIdx.x;
    int base = blockIdx.x * NPB + threadIdx.y * NPT;
    int ix[NPT] = {min(base + 0, N - 1), min(base + 1, N - 1), min(base + 2, N - 1),
                   min(base + 3, N - 1)};
    float s[NPT] = {0.f, 0.f, 0.f, 0.f};
#pragma unroll 2
    for (int f = 0; f < FIN; f += 4) {
        float w0 = sw[(f + 0) * FOUT + o], w1 = sw[(f + 1) * FOUT + o];
        float w2 = sw[(f + 2) * FOUT + o], w3 = sw[(f + 3) * FOUT + o];
#pragma unroll
        for (int k = 0; k < NPT; ++k) {
            float4 v = *(const float4*)(sd + (size_t)ix[k] * FIN + f);
            s[k] += v.x * w0 + v.y * w1 + v.z * w2 + v.w * w3;
        }
    }
    float mo = mw2[o], bo = b1w2[o], b2o = b2[o];
#pragma unroll
    for (int k = 0; k < NPT; ++k) {
        int i = base + k;
        if (i < N) {
            float deg = (float)cnt[i];
            float inv = 1.0f / (deg + 1.0f);
            out[(size_t)i * FOUT + o] = LRELU((s[k] + deg * mo + bo) * inv + b2o);
        }
    }
}

// ---------------- constants ---------------------------------------------------
__global__ void consts_k(const float* __restrict__ e0_b1, const float* __restrict__ e0_w2,
                         const float* __restrict__ e0_b2, const float* __restrict__ e1_b1,
                         const float* __restrict__ e1_w2, const float* __restrict__ e1_b2,
                         const float* __restrict__ e2_b1, const float* __restrict__ e2_w2,
                         const float* __restrict__ e2_b2, const float* __restrict__ e3_b1,
                         const float* __restrict__ e3_w2, const float* __restrict__ e3_b2,
                         const float* __restrict__ w12_1, const float* __restrict__ w12_2,
                         const float* __restrict__ w12_3, float* __restrict__ cbuf) {
    __shared__ float c1[64], c2[64], c3[32];
    int tid = threadIdx.x;  // 128 threads
    if (tid < 64) {
        float s = 0.0f;
#pragma unroll
        for (int k = 0; k < 128; ++k) s += e0_b1[k] * e0_w2[k * 64 + tid];
        cbuf[192 + tid] = s;
        c1[tid] = LRELU(s + e0_b2[tid]);
        cbuf[tid] = c1[tid];
    }
    if (tid < 64) {
        float s = 0.0f;
#pragma unroll
        for (int k = 0; k < 128; ++k) s += e1_b1[k] * e1_w2[k * 64 + tid];
        cbuf[256 + tid] = s;
        c2[tid] = LRELU(s + e1_b2[tid]);
        cbuf[64 + tid] = c2[tid];
    }
    if (tid < 32) {
        float s = 0.0f;
#pragma unroll
        for (int k = 0; k < 64; ++k) s += e2_b1[k] * e2_w2[k * 32 + tid];
        cbuf[384 + tid] = s;
        c3[tid] = LRELU(s + e2_b2[tid]);
        cbuf[128 + tid] = c3[tid];
    }
    if (tid < 32) {
        float s = 0.0f;
#pragma unroll
        for (int k = 0; k < 64; ++k) s += e3_b1[k] * e3_w2[k * 32 + tid];
        cbuf[448 + tid] = s;
        cbuf[160 + tid] = LRELU(s + e3_b2[tid]);  // c4
    }
    __syncthreads();
    if (tid < 64) {
        float s = cbuf[256 + tid];
#pragma unroll
        for (int f = 0; f < 64; ++f) s += c1[f] * w12_1[f * 64 + tid];
        cbuf[320 + tid] = s;
    }
    if (tid < 32) {
        float s = cbuf[384 + tid];
#pragma unroll
        for (int f = 0; f < 64; ++f) s += c2[f] * w12_2[f * 32 + tid];
        cbuf[416 + tid] = s;
    }
    if (tid < 32) {
        float s = cbuf[448 + tid];
#pragma unroll
        for (int f = 0; f < 32; ++f) s += c3[f] * w12_3[f * 32 + tid];
        cbuf[480 + tid] = s;
    }
}

// ---------------- final: bf16 h3 gathers, 2 edges/thread ---------------------
__device__ __forceinline__ float bdot8(uint4 a, uint4 b, const float* __restrict__ w) {
    return bf_lo(a.x) * bf_lo(b.x) * w[0] + bf_hi(a.x) * bf_hi(b.x) * w[1] +
           bf_lo(a.y) * bf_lo(b.y) * w[2] + bf_hi(a.y) * bf_hi(b.y) * w[3] +
           bf_lo(a.z) * bf_lo(b.z) * w[4] + bf_hi(a.z) * bf_hi(b.z) * w[5] +
           bf_lo(a.w) * bf_lo(b.w) * w[6] + bf_hi(a.w) * bf_hi(b.w) * w[7];
}

__global__ void final_k(const unsigned short* __restrict__ h3b, const float* __restrict__ dv3,
                        const float* __restrict__ c4, const int* __restrict__ row,
                        const int* __restrict__ col, const float* __restrict__ fcw,
                        const float* __restrict__ fcb, float* __restrict__ out, int E, int N) {
    __shared__ float sw[64];
    __shared__ float sc4[32];
    __shared__ float cdot_s;
    int tid = threadIdx.x;
    if (tid < 64) sw[tid] = fcw[tid];
    if (tid < 32) sc4[tid] = c4[tid];
    __syncthreads();
    if (tid == 0) {
        float cd = 0.0f;
#pragma unroll
        for (int k = 0; k < 32; ++k) cd += sc4[k] * sw[32 + k];
        cdot_s = cd;
    }
    __syncthreads();
    float fb = fcb[0];
    float cdot = cdot_s;
    int e0 = blockIdx.x * 512 + tid;
    int e1 = e0 + 256;
    bool v0 = e0 < E, v1 = e1 < E;
    int r0 = 0, c0 = 0, r1 = 0, c1 = 0;
    if (v0) { r0 = row[e0]; c0 = col[e0]; }
    if (v1) { r1 = row[e1]; c1 = col[e1]; }
    // issue all 16 h3 gathers + dv gathers before any dependent math
    uint4 a0[4], b0[4], a1[4], b1[4];
    float4 d0[8], d1[8];
    bool dv0 = v0 && e0 < N, dv1 = v1 && e1 < N;
    if (v0) {
        const uint4* pr = (const uint4*)(h3b + (size_t)r0 * 32);
        const uint4* pc = (const uint4*)(h3b + (size_t)c0 * 32);
#pragma unroll
        for (int q = 0; q < 4; ++q) { a0[q] = pr[q]; b0[q] = pc[q]; }
    }
    if (v1) {
        const uint4* pr = (const uint4*)(h3b + (size_t)r1 * 32);
        const uint4* pc = (const uint4*)(h3b + (size_t)c1 * 32);
#pragma unroll
        for (int q = 0; q < 4; ++q) { a1[q] = pr[q]; b1[q] = pc[q]; }
    }
    if (dv0) {
        const float4* dp = (const float4*)(dv3 + (size_t)e0 * 32);
#pragma unroll
        for (int q = 0; q < 8; ++q) d0[q] = dp[q];
    }
    if (dv1) {
        const float4* dp = (const float4*)(dv3 + (size_t)e1 * 32);
#pragma unroll
        for (int q = 0; q < 8; ++q) d1[q] = dp[q];
    }
    if (v0) {
        float s = fb;
#pragma unroll
        for (int q = 0; q < 4; ++q) s += bdot8(a0[q], b0[q], sw + q * 8);
        if (dv0) {
#pragma unroll
            for (int q = 0; q < 8; ++q) {
                float4 d = d0[q];
                s += d.x * sw[32 + q * 4 + 0] + d.y * sw[32 + q * 4 + 1] +
                     d.z * sw[32 + q * 4 + 2] + d.w * sw[32 + q * 4 + 3];
            }
        } else {
            s += cdot;
        }
        out[e0] = s;
    }
    if (v1) {
        float s = fb;
#pragma unroll
        for (int q = 0; q < 4; ++q) s += bdot8(a1[q], b1[q], sw + q * 8);
        if (dv1) {
#pragma unroll
            for (int q = 0; q < 8; ++q) {
                float4 d = d1[q];
                s += d.x * sw[32 + q * 4 + 0] + d.y * sw[32 + q * 4 + 1] +
                     d.z * sw[32 + q * 4 + 2] + d.w * sw[32 + q * 4 + 3];
            }
        } else {
            s += cdot;
        }
        out[e1] = s;
    }
}

extern "C" void kernel_launch(void* const* d_in, const int* in_sizes, int n_in, void* d_out,
                              int out_size, void* d_ws, size_t ws_size, hipStream_t stream) {
    const float* x = (const float*)d_in[0];
    const float* dis = (const float*)d_in[1];
    const int* ei = (const int*)d_in[2];
    const float* s_wl[4] = {(const float*)d_in[3], (const float*)d_in[6], (const float*)d_in[9],
                            (const float*)d_in[12]};
    const float* s_bl[4] = {(const float*)d_in[4], (const float*)d_in[7], (const float*)d_in[10],
                            (const float*)d_in[13]};
    const float* s_wr[4] = {(const float*)d_in[5], (const float*)d_in[8], (const float*)d_in[11],
                            (const float*)d_in[14]};
    const float* e_w1[4] = {(const float*)d_in[15], (const float*)d_in[19], (const float*)d_in[23],
                            (const float*)d_in[27]};
    const float* e_b1[4] = {(const float*)d_in[16], (const float*)d_in[20], (const float*)d_in[24],
                            (const float*)d_in[28]};
    const float* e_w2[4] = {(const float*)d_in[17], (const float*)d_in[21], (const float*)d_in[25],
                            (const float*)d_in[29]};
    const float* e_b2[4] = {(const float*)d_in[18], (const float*)d_in[22], (const float*)d_in[26],
                            (const float*)d_in[30]};
    const float* fcw = (const float*)d_in[31];
    const float* fcb = (const float*)d_in[32];

    const int N = in_sizes[0] / 64;
    const int E = in_sizes[1] / 8;
    const int* row = ei;
    const int* col = ei + E;
    const int NBUCK = (N + 127) / 128;
    const int EB = (E + 8191) / 8192;

    // ---- workspace carve (same footprint as R15-proven)
    auto au = [](size_t v) { return (v + 255) & ~(size_t)255; };
    char* p = (char*)d_ws;
    int* cnt = (int*)p;       p += au((size_t)N * 4);
    int* rowptr = (int*)p;    p += au((size_t)(N + 1) * 4);
    int* bcnt = (int*)p;      p += au(512 * 4);
    int* bbase = (int*)p;     p += au(513 * 4);
    int* bwp = (int*)p;       p += au(512 * 4);
    float* w12_0 = (float*)p; p += au(512 * 4);
    float* w12_1 = (float*)p; p += au(4096 * 4);
    float* w12_2 = (float*)p; p += au(2048 * 4);
    float* w12_3 = (float*)p; p += au(1024 * 4);
    float* cbuf = (float*)p;  p += au(512 * 4);
    int2* pairs = (int2*)p;   p += au((size_t)E * 8);
    float* acc = (float*)p;   p += au((size_t)N * 64 * 4);
    float* hA = (float*)p;    p += au((size_t)N * 64 * 4);
    float* hB = (float*)p;    p += au((size_t)N * 64 * 4);
    float* dvA = (float*)p;   p += au((size_t)N * 64 * 4);
    float* dvB = (float*)p;   p += au((size_t)N * 64 * 4);

    int2* tmp = (int2*)dvA;                      // bucket tmp (dvA idle until edge chain)
    unsigned short* hlb = (unsigned short*)acc;  // bf16 hl table (all layers)
    unsigned short* h3b = (unsigned short*)hA;   // bf16 h3

    // ---- two-level bucket CSR build
    hipMemsetAsync(bcnt, 0, 512 * 4, stream);
    bucket_count_k<<<EB, 1024, 0, stream>>>(col, bcnt, E);
    bucket_scan_k<<<1, 512, 0, stream>>>(bcnt, bbase, bwp, NBUCK, E);
    bucket_scatter_k<<<EB, 1024, 0, stream>>>(row, col, bwp, tmp, E);
    bucket_csr_k<<<NBUCK, 256, 0, stream>>>(tmp, bbase, rowptr, cnt, pairs, N, E);

    // ---- weight-only precompute
    gemm_w12_all_k<<<168, 64, 0, stream>>>(e_w1[0], e_w2[0], w12_0, e_w1[1], e_w2[1], w12_1,
                                           e_w1[2], e_w2[2], w12_2, e_w1[3], e_w2[3], w12_3);
    consts_k<<<1, 128, 0, stream>>>(e_b1[0], e_w2[0], e_b2[0], e_b1[1], e_w2[1], e_b2[1], e_b1[2],
                                    e_w2[2], e_b2[2], e_b1[3], e_w2[3], e_b2[3], w12_1, w12_2,
                                    w12_3, cbuf);

    const int WPB = 4;

    // ---- SAGE layer 0: x -> hA (64->64), bf16 table
    gemm2_k<64, 64, true><<<(N + 31) / 32, dim3(32, 8), 0, stream>>>(x, s_wl[0], s_wr[0], s_bl[0],
                                                                     hlb, dvB, N);
    aggr_fused64_bf_k<<<(N + WPB - 1) / WPB, 256, 0, stream>>>(hlb, dvB, rowptr, pairs, hA, N);
    // ---- SAGE layer 1: hA -> hB (64->64), bf16 table
    gemm2_k<64, 64, true><<<(N + 31) / 32, dim3(32, 8), 0, stream>>>(hA, s_wl[1], s_wr[1], s_bl[1],
                                                                     hlb, dvB, N);
    aggr_fused64_bf_k<<<(N + WPB - 1) / WPB, 256, 0, stream>>>(hlb, dvB, rowptr, pairs, hB, N);
    // ---- SAGE layer 2: hB -> hA (64->32), bf16 table, fp32 output
    gemm2_k<64, 32, true><<<(N + 63) / 64, dim3(16, 16), 0, stream>>>(hB, s_wl[2], s_wr[2],
                                                                      s_bl[2], hlb, dvB, N);
    aggr_fused32_bf_k<false><<<(N + WPB - 1) / WPB, 256, 0, stream>>>(hlb, dvB, rowptr, pairs, hA,
                                                                      N);
    // ---- SAGE layer 3: hA -> h3b (32->32), bf16 table, bf16 output
    gemm2_k<32, 32, true><<<(N + 63) / 64, dim3(16, 16), 0, stream>>>(hA, s_wl[3], s_wr[3],
                                                                      s_bl[3], hlb, dvB, N);
    aggr_fused32_bf_k<true><<<(N + WPB - 1) / WPB, 256, 0, stream>>>(hlb, dvB, rowptr, pairs, h3b,
                                                                     N);

    // ---- edge conv chain (fused compute+scatter)
    edge_aggr8_k<<<(N + WPB - 1) / WPB, 256, 0, stream>>>(dis, rowptr, pairs, acc, N);
    hipMemsetAsync(dvA, 0, (size_t)N * 64 * 4, stream);
    edge_compute_scatter_k<8, 64><<<(N + 15) / 16, dim3(64, 4), 0, stream>>>(
        acc, cnt, w12_0, cbuf + 192, cbuf + 192, e_b2[0], cbuf + 0, col, dvA, N);
    hipMemsetAsync(acc, 0, (size_t)N * 64 * 4, stream);
    edge_compute_scatter_k<64, 64><<<(N + 15) / 16, dim3(64, 4), 0, stream>>>(
        dvA, cnt, w12_1, cbuf + 320, cbuf + 256, e_b2[1], cbuf + 64, col, acc, N);
    hipMemsetAsync(dvA, 0, (size_t)N * 32 * 4, stream);
    edge_compute_scatter_k<64, 32><<<(N + 31) / 32, dim3(32, 8), 0, stream>>>(
        acc, cnt, w12_2, cbuf + 416, cbuf + 384, e_b2[2], cbuf + 128, col, dvA, N);
    edge_compute2_k<32, 32><<<(N + 31) / 32, dim3(32, 8), 0, stream>>>(
        dvA, cnt, w12_3, cbuf + 480, cbuf + 448, e_b2[3], dvB, N);

    // ---- final per-edge output (bf16 h3 gathers, 2 edges/thread)
    final_k<<<(E + 511) / 512, 256, 0, stream>>>(h3b, dvB, cbuf + 160, row, col, fcw, fcb,
                                                 (float*)d_out, E, N);
}

// Round 17
// 477.348 us; speedup vs baseline: 1.0207x; 1.0207x over previous
//
#include <hip/hip_runtime.h>

#define LRELU(v) ((v) > 0.0f ? (v) : 0.01f * (v))

__device__ __forceinline__ unsigned short f2bf(float f) {
    union { float f; unsigned u; } c;
    c.f = f;
    return (unsigned short)((c.u + 0x7fffu + ((c.u >> 16) & 1)) >> 16);
}
__device__ __forceinline__ float bf_lo(unsigned u) {
    union { unsigned i; float f; } v;
    v.i = u << 16;
    return v.f;
}
__device__ __forceinline__ float bf_hi(unsigned u) {
    union { unsigned i; float f; } v;
    v.i = u & 0xffff0000u;
    return v.f;
}

// ================= two-level bucket CSR build ================================
__global__ void bucket_count_k(const int* __restrict__ col, int* __restrict__ bcnt, int E) {
    __shared__ int lcnt[512];
    int tid = threadIdx.x;  // 1024
    for (int i = tid; i < 512; i += 1024) lcnt[i] = 0;
    __syncthreads();
    int base = blockIdx.x * 8192;
    for (int k = 0; k < 8; ++k) {
        int e = base + k * 1024 + tid;
        if (e < E) atomicAdd(&lcnt[col[e] >> 7], 1);
    }
    __syncthreads();
    for (int i = tid; i < 512; i += 1024) {
        int v = lcnt[i];
        if (v) atomicAdd(&bcnt[i], v);
    }
}

__global__ void bucket_scan_k(const int* __restrict__ bcnt, int* __restrict__ bbase,
                              int* __restrict__ bwp, int NBUCK, int E) {
    __shared__ int s[512];
    int tid = threadIdx.x;  // 512
    int v = (tid < NBUCK) ? bcnt[tid] : 0;
    s[tid] = v;
    __syncthreads();
    for (int off = 1; off < 512; off <<= 1) {
        int t = (tid >= off) ? s[tid - off] : 0;
        __syncthreads();
        s[tid] += t;
        __syncthreads();
    }
    if (tid < NBUCK) {
        int ex = s[tid] - v;
        bbase[tid] = ex;
        bwp[tid] = ex;
    }
    if (tid == 0) bbase[NBUCK] = E;
}

__global__ void bucket_scatter_k(const int* __restrict__ row, const int* __restrict__ col,
                                 int* __restrict__ bwp, int2* __restrict__ tmp, int E) {
    __shared__ int lcnt[512];
    __shared__ int gbase[512];
    int tid = threadIdx.x;  // 1024
    for (int i = tid; i < 512; i += 1024) lcnt[i] = 0;
    __syncthreads();
    int base = blockIdx.x * 8192;
    int lpos[8], bk[8];
    for (int k = 0; k < 8; ++k) {
        int e = base + k * 1024 + tid;
        if (e < E) {
            int b = col[e] >> 7;
            bk[k] = b;
            lpos[k] = atomicAdd(&lcnt[b], 1);
        } else
            bk[k] = -1;
    }
    __syncthreads();
    for (int i = tid; i < 512; i += 1024) {
        int v = lcnt[i];
        gbase[i] = v ? atomicAdd(&bwp[i], v) : 0;
    }
    __syncthreads();
    for (int k = 0; k < 8; ++k) {
        int e = base + k * 1024 + tid;
        if (e < E) {
            int c = col[e];
            tmp[gbase[bk[k]] + lpos[k]] = make_int2(row[e], ((c & 127) << 25) | e);
        }
    }
}

__global__ void bucket_csr_k(const int2* __restrict__ tmp, const int* __restrict__ bbase,
                             int* __restrict__ rowptr, int* __restrict__ cnt,
                             int2* __restrict__ pairs, int N, int E) {
    constexpr int CAP = 6144;
    __shared__ int2 buf[CAP];
    __shared__ int lcnt[128];
    __shared__ int sscan[128];
    __shared__ int lwp[128];
    int b = blockIdx.x;
    int tid = threadIdx.x;  // 256
    int s = bbase[b], e = bbase[b + 1];
    int sz = e - s;
    if (tid < 128) lcnt[tid] = 0;
    __syncthreads();
    for (int i = tid; i < sz; i += 256) {
        int2 v = tmp[s + i];
        if (i < CAP) buf[i] = v;
        atomicAdd(&lcnt[((unsigned)v.y) >> 25], 1);
    }
    __syncthreads();
    if (tid < 128) sscan[tid] = lcnt[tid];
    __syncthreads();
    for (int off = 1; off < 128; off <<= 1) {
        int t = (tid < 128 && tid >= off) ? sscan[tid - off] : 0;
        __syncthreads();
        if (tid < 128) sscan[tid] += t;
        __syncthreads();
    }
    if (tid < 128) {
        int ex = sscan[tid] - lcnt[tid];
        lwp[tid] = ex;
        int c = b * 128 + tid;
        if (c < N) {
            rowptr[c] = s + ex;
            cnt[c] = lcnt[tid];
            if (c == N - 1) rowptr[N] = E;
        }
    }
    __syncthreads();
    for (int i = tid; i < sz; i += 256) {
        int2 v = (i < CAP) ? buf[i] : tmp[s + i];
        int cl = ((unsigned)v.y) >> 25;
        int p = atomicAdd(&lwp[cl], 1);
        pairs[s + p] = make_int2(v.x, v.y & 0x1FFFFFF);
    }
}

// ---------------- dual GEMM: hl = h@wl (fp32 or bf16), hr = h@wr + bl --------
template <int FIN, int FOUT, bool BFL>
__global__ void gemm2_k(const float* __restrict__ h, const float* __restrict__ wl,
                        const float* __restrict__ wr, const float* __restrict__ bl,
                        void* __restrict__ hl, float* __restrict__ hr, int N) {
    constexpr int XT = (2 * FOUT) / 4;
    constexpr int YT = 256 / XT;
    constexpr int NPT = 4;
    constexpr int NPB = YT * NPT;
    __shared__ float sw[FIN * 2 * FOUT];
    int lin = threadIdx.y * XT + threadIdx.x;
    for (int idx = lin; idx < FIN * FOUT; idx += 256) {
        int f = idx / FOUT, o = idx % FOUT;
        sw[f * 2 * FOUT + o] = wl[idx];
        sw[f * 2 * FOUT + FOUT + o] = wr[idx];
    }
    __syncthreads();
    int og = threadIdx.x * 4;
    int base = blockIdx.x * NPB + threadIdx.y * NPT;
    int ix[NPT] = {min(base + 0, N - 1), min(base + 1, N - 1), min(base + 2, N - 1),
                   min(base + 3, N - 1)};
    float4 s[NPT] = {{0.f, 0.f, 0.f, 0.f}, {0.f, 0.f, 0.f, 0.f}, {0.f, 0.f, 0.f, 0.f},
                     {0.f, 0.f, 0.f, 0.f}};
#pragma unroll 2
    for (int f = 0; f < FIN; f += 4) {
        float4 w0 = *(const float4*)&sw[(f + 0) * 2 * FOUT + og];
        float4 w1 = *(const float4*)&sw[(f + 1) * 2 * FOUT + og];
        float4 w2 = *(const float4*)&sw[(f + 2) * 2 * FOUT + og];
        float4 w3 = *(const float4*)&sw[(f + 3) * 2 * FOUT + og];
#pragma unroll
        for (int k = 0; k < NPT; ++k) {
            float4 v = *(const float4*)(h + (size_t)ix[k] * FIN + f);
            s[k].x += v.x * w0.x + v.y * w1.x + v.z * w2.x + v.w * w3.x;
            s[k].y += v.x * w0.y + v.y * w1.y + v.z * w2.y + v.w * w3.y;
            s[k].z += v.x * w0.z + v.y * w1.z + v.z * w2.z + v.w * w3.z;
            s[k].w += v.x * w0.w + v.y * w1.w + v.z * w2.w + v.w * w3.w;
        }
    }
    bool isR = og >= FOUT;
    int oo = isR ? og - FOUT : og;
    if (isR) {
        float4 bias = *(const float4*)&bl[oo];
#pragma unroll
        for (int k = 0; k < NPT; ++k) {
            int i = base + k;
            if (i < N) {
                float4 r = {s[k].x + bias.x, s[k].y + bias.y, s[k].z + bias.z, s[k].w + bias.w};
                *(float4*)(hr + (size_t)i * FOUT + oo) = r;
            }
        }
    } else {
#pragma unroll
        for (int k = 0; k < NPT; ++k) {
            int i = base + k;
            if (i < N) {
                if (BFL) {
                    unsigned short* d = (unsigned short*)hl + (size_t)i * FOUT + oo;
                    *(ushort4*)d =
                        make_ushort4(f2bf(s[k].x), f2bf(s[k].y), f2bf(s[k].z), f2bf(s[k].w));
                } else {
                    *(float4*)((float*)hl + (size_t)i * FOUT + oo) = s[k];
                }
            }
        }
    }
}

// ---------------- fused SAGE aggregate+epilogue, 64-wide, bf16 table ---------
// wave = 4 rows x 16 lanes (uint2 = 4 bf16 elems each); unroll 2 for MLP.
__global__ void aggr_fused64_bf_k(const unsigned short* __restrict__ hlb,
                                  const float* __restrict__ hr, const int* __restrict__ rowptr,
                                  const int2* __restrict__ pairs, float* __restrict__ out, int N) {
    int wave = (blockIdx.x * blockDim.x + threadIdx.x) >> 6;
    int lane = threadIdx.x & 63;
    if (wave >= N) return;
    int u = lane >> 4, f4 = lane & 15;
    int s = rowptr[wave], e = rowptr[wave + 1];
    float4 a = {0.f, 0.f, 0.f, 0.f};
    int p = s + u;
    for (; p + 4 < e; p += 8) {
        int r0 = pairs[p].x, r1 = pairs[p + 4].x;
        uint2 v0 = ((const uint2*)(hlb + (size_t)r0 * 64))[f4];
        uint2 v1 = ((const uint2*)(hlb + (size_t)r1 * 64))[f4];
        a.x += bf_lo(v0.x) + bf_lo(v1.x);
        a.y += bf_hi(v0.x) + bf_hi(v1.x);
        a.z += bf_lo(v0.y) + bf_lo(v1.y);
        a.w += bf_hi(v0.y) + bf_hi(v1.y);
    }
    if (p < e) {
        uint2 v = ((const uint2*)(hlb + (size_t)pairs[p].x * 64))[f4];
        a.x += bf_lo(v.x); a.y += bf_hi(v.x); a.z += bf_lo(v.y); a.w += bf_hi(v.y);
    }
    a.x += __shfl_down(a.x, 32); a.y += __shfl_down(a.y, 32);
    a.z += __shfl_down(a.z, 32); a.w += __shfl_down(a.w, 32);
    a.x += __shfl_down(a.x, 16); a.y += __shfl_down(a.y, 16);
    a.z += __shfl_down(a.z, 16); a.w += __shfl_down(a.w, 16);
    if (lane < 16) {
        float inv = 1.0f / fmaxf((float)(e - s), 1.0f);
        float4 r = ((const float4*)(hr + (size_t)wave * 64))[f4];
        float4 o;
        o.x = LRELU(a.x * inv + r.x);
        o.y = LRELU(a.y * inv + r.y);
        o.z = LRELU(a.z * inv + r.z);
        o.w = LRELU(a.w * inv + r.w);
        ((float4*)(out + (size_t)wave * 64))[f4] = o;
    }
}

// ---------------- fused SAGE aggregate+epilogue, 32-wide, bf16 table ---------
// wave = 8 rows x 8 lanes (uint2 = 4 bf16 elems each); unroll 2.
// OUTBF=true writes bf16 output (final layer -> h3b), else fp32.
template <bool OUTBF>
__global__ void aggr_fused32_bf_k(const unsigned short* __restrict__ hlb,
                                  const float* __restrict__ hr, const int* __restrict__ rowptr,
                                  const int2* __restrict__ pairs, void* __restrict__ out, int N) {
    int wave = (blockIdx.x * blockDim.x + threadIdx.x) >> 6;
    int lane = threadIdx.x & 63;
    if (wave >= N) return;
    int u = lane >> 3, f4 = lane & 7;
    int s = rowptr[wave], e = rowptr[wave + 1];
    float4 a = {0.f, 0.f, 0.f, 0.f};
    int p = s + u;
    for (; p + 8 < e; p += 16) {
        int r0 = pairs[p].x, r1 = pairs[p + 8].x;
        uint2 v0 = ((const uint2*)(hlb + (size_t)r0 * 32))[f4];
        uint2 v1 = ((const uint2*)(hlb + (size_t)r1 * 32))[f4];
        a.x += bf_lo(v0.x) + bf_lo(v1.x);
        a.y += bf_hi(v0.x) + bf_hi(v1.x);
        a.z += bf_lo(v0.y) + bf_lo(v1.y);
        a.w += bf_hi(v0.y) + bf_hi(v1.y);
    }
    if (p < e) {
        uint2 v = ((const uint2*)(hlb + (size_t)pairs[p].x * 32))[f4];
        a.x += bf_lo(v.x); a.y += bf_hi(v.x); a.z += bf_lo(v.y); a.w += bf_hi(v.y);
    }
    a.x += __shfl_down(a.x, 32); a.y += __shfl_down(a.y, 32);
    a.z += __shfl_down(a.z, 32); a.w += __shfl_down(a.w, 32);
    a.x += __shfl_down(a.x, 16); a.y += __shfl_down(a.y, 16);
    a.z += __shfl_down(a.z, 16); a.w += __shfl_down(a.w, 16);
    a.x += __shfl_down(a.x, 8); a.y += __shfl_down(a.y, 8);
    a.z += __shfl_down(a.z, 8); a.w += __shfl_down(a.w, 8);
    if (lane < 8) {
        float inv = 1.0f / fmaxf((float)(e - s), 1.0f);
        const float4* hp = (const float4*)(hr + (size_t)wave * 32);
        float4 r = hp[f4];
        float4 o;
        o.x = LRELU(a.x * inv + r.x);
        o.y = LRELU(a.y * inv + r.y);
        o.z = LRELU(a.z * inv + r.z);
        o.w = LRELU(a.w * inv + r.w);
        if (OUTBF) {
            unsigned short* d = (unsigned short*)out + (size_t)wave * 32 + f4 * 4;
            *(ushort4*)d = make_ushort4(f2bf(o.x), f2bf(o.y), f2bf(o.z), f2bf(o.w));
        } else {
            ((float4*)((float*)out + (size_t)wave * 32))[f4] = o;
        }
    }
}

// ---------------- edge conv layer 0: wave = 32 neighbors x 2 f4-lanes --------
__global__ void edge_aggr8_k(const float* __restrict__ dis, const int* __restrict__ rowptr,
                             const int2* __restrict__ pairs, float* __restrict__ sd, int N) {
    int wave = (blockIdx.x * blockDim.x + threadIdx.x) >> 6;
    int lane = threadIdx.x & 63;
    if (wave >= N) return;
    int u = lane >> 1, f4 = lane & 1;
    int s = rowptr[wave], e = rowptr[wave + 1];
    float4 a = {0.f, 0.f, 0.f, 0.f};
    for (int p = s + u; p < e; p += 32) {
        const float4* dp = (const float4*)(dis + (size_t)pairs[p].y * 8);
        float4 v = dp[f4];
        a.x += v.x; a.y += v.y; a.z += v.z; a.w += v.w;
    }
    for (int off = 32; off >= 2; off >>= 1) {
        a.x += __shfl_down(a.x, off); a.y += __shfl_down(a.y, off);
        a.z += __shfl_down(a.z, off); a.w += __shfl_down(a.w, off);
    }
    if (lane < 2) ((float4*)(sd + (size_t)wave * 8))[f4] = a;
}

// ---------------- all four W12 = w1 @ w2 in one launch (templated bodies) ----
template <int H2, int HOUT>
__device__ __forceinline__ void w12_body(const float* __restrict__ w1,
                                         const float* __restrict__ w2, float* __restrict__ out,
                                         int i, int o) {
    float s = 0.0f;
#pragma unroll
    for (int k = 0; k < H2; ++k) s += w1[i * H2 + k] * w2[k * HOUT + o];
    out[i * HOUT + o] = s;
}

__global__ void gemm_w12_all_k(const float* __restrict__ w1_0, const float* __restrict__ w2_0,
                               float* __restrict__ o0, const float* __restrict__ w1_1,
                               const float* __restrict__ w2_1, float* __restrict__ o1,
                               const float* __restrict__ w1_2, const float* __restrict__ w2_2,
                               float* __restrict__ o2, const float* __restrict__ w1_3,
                               const float* __restrict__ w2_3, float* __restrict__ o3) {
    int b = blockIdx.x;
    int o = threadIdx.x;
    if (b < 8) {
        w12_body<128, 64>(w1_0, w2_0, o0, b, o);
    } else if (b < 72) {
        w12_body<128, 64>(w1_1, w2_1, o1, b - 8, o);
    } else if (b < 136) {
        if (o < 32) w12_body<64, 32>(w1_2, w2_2, o2, b - 72, o);
    } else {
        if (o < 32) w12_body<64, 32>(w1_3, w2_3, o3, b - 136, o);
    }
}

// ---------------- collapsed edge conv + fused next-layer delta scatter -------
template <int FIN, int FOUT>
__global__ void edge_compute_scatter_k(const float* __restrict__ sd, const int* __restrict__ cnt,
                                       const float* __restrict__ w12, const float* __restrict__ mw2,
                                       const float* __restrict__ b1w2, const float* __restrict__ b2,
                                       const float* __restrict__ cnext,
                                       const int* __restrict__ col, float* __restrict__ sdnext,
                                       int N) {
    constexpr int ROWS = 256 / FOUT;
    constexpr int NPT = 4;
    constexpr int NPB = ROWS * NPT;
    __shared__ float sw[FIN * FOUT];
    int lin = threadIdx.y * FOUT + threadIdx.x;
    for (int idx = lin; idx < FIN * FOUT; idx += 256) sw[idx] = w12[idx];
    __syncthreads();
    int o = threadIdx.x;
    int base = blockIdx.x * NPB + threadIdx.y * NPT;
    int ix[NPT] = {min(base + 0, N - 1), min(base + 1, N - 1), min(base + 2, N - 1),
                   min(base + 3, N - 1)};
    float s[NPT] = {0.f, 0.f, 0.f, 0.f};
#pragma unroll 2
    for (int f = 0; f < FIN; f += 4) {
        float w0 = sw[(f + 0) * FOUT + o], w1 = sw[(f + 1) * FOUT + o];
        float w2 = sw[(f + 2) * FOUT + o], w3 = sw[(f + 3) * FOUT + o];
#pragma unroll
        for (int k = 0; k < NPT; ++k) {
            float4 v = *(const float4*)(sd + (size_t)ix[k] * FIN + f);
            s[k] += v.x * w0 + v.y * w1 + v.z * w2 + v.w * w3;
        }
    }
    float mo = mw2[o], bo = b1w2[o], b2o = b2[o], co = cnext[o];
#pragma unroll
    for (int k = 0; k < NPT; ++k) {
        int i = base + k;
        if (i < N) {
            float deg = (float)cnt[i];
            float inv = 1.0f / (deg + 1.0f);
            float val = LRELU((s[k] + deg * mo + bo) * inv + b2o);
            atomicAdd(&sdnext[(size_t)col[i] * FOUT + o], val - co);
        }
    }
}

// ---------------- last edge conv: plain output write -------------------------
template <int FIN, int FOUT>
__global__ void edge_compute2_k(const float* __restrict__ sd, const int* __restrict__ cnt,
                                const float* __restrict__ w12, const float* __restrict__ mw2,
                                const float* __restrict__ b1w2, const float* __restrict__ b2,
                                float* __restrict__ out, int N) {
    constexpr int ROWS = 256 / FOUT;
    constexpr int NPT = 4;
    constexpr int NPB = ROWS * NPT;
    __shared__ float sw[FIN * FOUT];
    int lin = threadIdx.y * FOUT + threadIdx.x;
    for (int idx = lin; idx < FIN * FOUT; idx += 256) sw[idx] = w12[idx];
    __syncthreads();
    int o = threadIdx.x;
    int base = blockIdx.x * NPB + threadIdx.y * NPT;
    int ix[NPT] = {min(base + 0, N - 1), min(base + 1, N - 1), min(base + 2, N - 1),
                   min(base + 3, N - 1)};
    float s[NPT] = {0.f, 0.f, 0.f, 0.f};
#pragma unroll 2
    for (int f = 0; f < FIN; f += 4) {
        float w0 = sw[(f + 0) * FOUT + o], w1 = sw[(f + 1) * FOUT + o];
        float w2 = sw[(f + 2) * FOUT + o], w3 = sw[(f + 3) * FOUT + o];
#pragma unroll
        for (int k = 0; k < NPT; ++k) {
            float4 v = *(const float4*)(sd + (size_t)ix[k] * FIN + f);
            s[k] += v.x * w0 + v.y * w1 + v.z * w2 + v.w * w3;
        }
    }
    float mo = mw2[o], bo = b1w2[o], b2o = b2[o];
#pragma unroll
    for (int k = 0; k < NPT; ++k) {
        int i = base + k;
        if (i < N) {
            float deg = (float)cnt[i];
            float inv = 1.0f / (deg + 1.0f);
            out[(size_t)i * FOUT + o] = LRELU((s[k] + deg * mo + bo) * inv + b2o);
        }
    }
}

// ---------------- constants ---------------------------------------------------
__global__ void consts_k(const float* __restrict__ e0_b1, const float* __restrict__ e0_w2,
                         const float* __restrict__ e0_b2, const float* __restrict__ e1_b1,
                         const float* __restrict__ e1_w2, const float* __restrict__ e1_b2,
                         const float* __restrict__ e2_b1, const float* __restrict__ e2_w2,
                         const float* __restrict__ e2_b2, const float* __restrict__ e3_b1,
                         const float* __restrict__ e3_w2, const float* __restrict__ e3_b2,
                         const float* __restrict__ w12_1, const float* __restrict__ w12_2,
                         const float* __restrict__ w12_3, float* __restrict__ cbuf) {
    __shared__ float c1[64], c2[64], c3[32];
    int tid = threadIdx.x;  // 128 threads
    if (tid < 64) {
        float s = 0.0f;
#pragma unroll
        for (int k = 0; k < 128; ++k) s += e0_b1[k] * e0_w2[k * 64 + tid];
        cbuf[192 + tid] = s;
        c1[tid] = LRELU(s + e0_b2[tid]);
        cbuf[tid] = c1[tid];
    }
    if (tid < 64) {
        float s = 0.0f;
#pragma unroll
        for (int k = 0; k < 128; ++k) s += e1_b1[k] * e1_w2[k * 64 + tid];
        cbuf[256 + tid] = s;
        c2[tid] = LRELU(s + e1_b2[tid]);
        cbuf[64 + tid] = c2[tid];
    }
    if (tid < 32) {
        float s = 0.0f;
#pragma unroll
        for (int k = 0; k < 64; ++k) s += e2_b1[k] * e2_w2[k * 32 + tid];
        cbuf[384 + tid] = s;
        c3[tid] = LRELU(s + e2_b2[tid]);
        cbuf[128 + tid] = c3[tid];
    }
    if (tid < 32) {
        float s = 0.0f;
#pragma unroll
        for (int k = 0; k < 64; ++k) s += e3_b1[k] * e3_w2[k * 32 + tid];
        cbuf[448 + tid] = s;
        cbuf[160 + tid] = LRELU(s + e3_b2[tid]);  // c4
    }
    __syncthreads();
    if (tid < 64) {
        float s = cbuf[256 + tid];
#pragma unroll
        for (int f = 0; f < 64; ++f) s += c1[f] * w12_1[f * 64 + tid];
        cbuf[320 + tid] = s;
    }
    if (tid < 32) {
        float s = cbuf[384 + tid];
#pragma unroll
        for (int f = 0; f < 64; ++f) s += c2[f] * w12_2[f * 32 + tid];
        cbuf[416 + tid] = s;
    }
    if (tid < 32) {
        float s = cbuf[448 + tid];
#pragma unroll
        for (int f = 0; f < 32; ++f) s += c3[f] * w12_3[f * 32 + tid];
        cbuf[480 + tid] = s;
    }
}

// ---------------- final: bf16 h3 gathers, 2 edges/thread ---------------------
__device__ __forceinline__ float bdot8(uint4 a, uint4 b, const float* __restrict__ w) {
    return bf_lo(a.x) * bf_lo(b.x) * w[0] + bf_hi(a.x) * bf_hi(b.x) * w[1] +
           bf_lo(a.y) * bf_lo(b.y) * w[2] + bf_hi(a.y) * bf_hi(b.y) * w[3] +
           bf_lo(a.z) * bf_lo(b.z) * w[4] + bf_hi(a.z) * bf_hi(b.z) * w[5] +
           bf_lo(a.w) * bf_lo(b.w) * w[6] + bf_hi(a.w) * bf_hi(b.w) * w[7];
}

__global__ void final_k(const unsigned short* __restrict__ h3b, const float* __restrict__ dv3,
                        const float* __restrict__ c4, const int* __restrict__ row,
                        const int* __restrict__ col, const float* __restrict__ fcw,
                        const float* __restrict__ fcb, float* __restrict__ out, int E, int N) {
    __shared__ float sw[64];
    __shared__ float sc4[32];
    __shared__ float cdot_s;
    int tid = threadIdx.x;
    if (tid < 64) sw[tid] = fcw[tid];
    if (tid < 32) sc4[tid] = c4[tid];
    __syncthreads();
    if (tid == 0) {
        float cd = 0.0f;
#pragma unroll
        for (int k = 0; k < 32; ++k) cd += sc4[k] * sw[32 + k];
        cdot_s = cd;
    }
    __syncthreads();
    float fb = fcb[0];
    float cdot = cdot_s;
    int e0 = blockIdx.x * 512 + tid;
    int e1 = e0 + 256;
    bool v0 = e0 < E, v1 = e1 < E;
    int r0 = 0, c0 = 0, r1 = 0, c1 = 0;
    if (v0) { r0 = row[e0]; c0 = col[e0]; }
    if (v1) { r1 = row[e1]; c1 = col[e1]; }
    uint4 a00, a01, b00, b01, a10, a11, b10, b11;
    if (v0) {
        const uint4* pr = (const uint4*)(h3b + (size_t)r0 * 32);
        const uint4* pc = (const uint4*)(h3b + (size_t)c0 * 32);
        a00 = pr[0]; a01 = pr[1]; b00 = pc[0]; b01 = pc[1];
    }
    if (v1) {
        const uint4* pr = (const uint4*)(h3b + (size_t)r1 * 32);
        const uint4* pc = (const uint4*)(h3b + (size_t)c1 * 32);
        a10 = pr[0]; a11 = pr[1]; b10 = pc[0]; b11 = pc[1];
    }
    if (v0) {
        float s = fb + bdot8(a00, b00, sw) + bdot8(a01, b01, sw + 8) +
                  bdot8(((const uint4*)(h3b + (size_t)r0 * 32))[2],
                        ((const uint4*)(h3b + (size_t)c0 * 32))[2], sw + 16) +
                  bdot8(((const uint4*)(h3b + (size_t)r0 * 32))[3],
                        ((const uint4*)(h3b + (size_t)c0 * 32))[3], sw + 24);
        if (e0 < N) {
            const float4* dp = (const float4*)(dv3 + (size_t)e0 * 32);
#pragma unroll
            for (int q = 0; q < 8; ++q) {
                float4 d = dp[q];
                s += d.x * sw[32 + q * 4 + 0] + d.y * sw[32 + q * 4 + 1] +
                     d.z * sw[32 + q * 4 + 2] + d.w * sw[32 + q * 4 + 3];
            }
        } else {
            s += cdot;
        }
        out[e0] = s;
    }
    if (v1) {
        float s = fb + bdot8(a10, b10, sw) + bdot8(a11, b11, sw + 8) +
                  bdot8(((const uint4*)(h3b + (size_t)r1 * 32))[2],
                        ((const uint4*)(h3b + (size_t)c1 * 32))[2], sw + 16) +
                  bdot8(((const uint4*)(h3b + (size_t)r1 * 32))[3],
                        ((const uint4*)(h3b + (size_t)c1 * 32))[3], sw + 24);
        if (e1 < N) {
            const float4* dp = (const float4*)(dv3 + (size_t)e1 * 32);
#pragma unroll
            for (int q = 0; q < 8; ++q) {
                float4 d = dp[q];
                s += d.x * sw[32 + q * 4 + 0] + d.y * sw[32 + q * 4 + 1] +
                     d.z * sw[32 + q * 4 + 2] + d.w * sw[32 + q * 4 + 3];
            }
        } else {
            s += cdot;
        }
        out[e1] = s;
    }
}

extern "C" void kernel_launch(void* const* d_in, const int* in_sizes, int n_in, void* d_out,
                              int out_size, void* d_ws, size_t ws_size, hipStream_t stream) {
    const float* x = (const float*)d_in[0];
    const float* dis = (const float*)d_in[1];
    const int* ei = (const int*)d_in[2];
    const float* s_wl[4] = {(const float*)d_in[3], (const float*)d_in[6], (const float*)d_in[9],
                            (const float*)d_in[12]};
    const float* s_bl[4] = {(const float*)d_in[4], (const float*)d_in[7], (const float*)d_in[10],
                            (const float*)d_in[13]};
    const float* s_wr[4] = {(const float*)d_in[5], (const float*)d_in[8], (const float*)d_in[11],
                            (const float*)d_in[14]};
    const float* e_w1[4] = {(const float*)d_in[15], (const float*)d_in[19], (const float*)d_in[23],
                            (const float*)d_in[27]};
    const float* e_b1[4] = {(const float*)d_in[16], (const float*)d_in[20], (const float*)d_in[24],
                            (const float*)d_in[28]};
    const float* e_w2[4] = {(const float*)d_in[17], (const float*)d_in[21], (const float*)d_in[25],
                            (const float*)d_in[29]};
    const float* e_b2[4] = {(const float*)d_in[18], (const float*)d_in[22], (const float*)d_in[26],
                            (const float*)d_in[30]};
    const float* fcw = (const float*)d_in[31];
    const float* fcb = (const float*)d_in[32];

    const int N = in_sizes[0] / 64;
    const int E = in_sizes[1] / 8;
    const int* row = ei;
    const int* col = ei + E;
    const int NBUCK = (N + 127) / 128;
    const int EB = (E + 8191) / 8192;

    // ---- workspace carve (same footprint as R15-proven)
    auto au = [](size_t v) { return (v + 255) & ~(size_t)255; };
    char* p = (char*)d_ws;
    int* cnt = (int*)p;       p += au((size_t)N * 4);
    int* rowptr = (int*)p;    p += au((size_t)(N + 1) * 4);
    int* bcnt = (int*)p;      p += au(512 * 4);
    int* bbase = (int*)p;     p += au(513 * 4);
    int* bwp = (int*)p;       p += au(512 * 4);
    float* w12_0 = (float*)p; p += au(512 * 4);
    float* w12_1 = (float*)p; p += au(4096 * 4);
    float* w12_2 = (float*)p; p += au(2048 * 4);
    float* w12_3 = (float*)p; p += au(1024 * 4);
    float* cbuf = (float*)p;  p += au(512 * 4);
    int2* pairs = (int2*)p;   p += au((size_t)E * 8);
    float* acc = (float*)p;   p += au((size_t)N * 64 * 4);
    float* hA = (float*)p;    p += au((size_t)N * 64 * 4);
    float* hB = (float*)p;    p += au((size_t)N * 64 * 4);
    float* dvA = (float*)p;   p += au((size_t)N * 64 * 4);
    float* dvB = (float*)p;   p += au((size_t)N * 64 * 4);

    int2* tmp = (int2*)dvA;                      // bucket tmp (dvA idle until edge chain)
    unsigned short* hlb = (unsigned short*)acc;  // bf16 hl table (all layers)
    unsigned short* h3b = (unsigned short*)hA;   // bf16 h3

    // ---- two-level bucket CSR build
    hipMemsetAsync(bcnt, 0, 512 * 4, stream);
    bucket_count_k<<<EB, 1024, 0, stream>>>(col, bcnt, E);
    bucket_scan_k<<<1, 512, 0, stream>>>(bcnt, bbase, bwp, NBUCK, E);
    bucket_scatter_k<<<EB, 1024, 0, stream>>>(row, col, bwp, tmp, E);
    bucket_csr_k<<<NBUCK, 256, 0, stream>>>(tmp, bbase, rowptr, cnt, pairs, N, E);

    // ---- weight-only precompute
    gemm_w12_all_k<<<168, 64, 0, stream>>>(e_w1[0], e_w2[0], w12_0, e_w1[1], e_w2[1], w12_1,
                                           e_w1[2], e_w2[2], w12_2, e_w1[3], e_w2[3], w12_3);
    consts_k<<<1, 128, 0, stream>>>(e_b1[0], e_w2[0], e_b2[0], e_b1[1], e_w2[1], e_b2[1], e_b1[2],
                                    e_w2[2], e_b2[2], e_b1[3], e_w2[3], e_b2[3], w12_1, w12_2,
                                    w12_3, cbuf);

    const int WPB = 4;

    // ---- SAGE layer 0: x -> hA (64->64), bf16 table
    gemm2_k<64, 64, true><<<(N + 31) / 32, dim3(32, 8), 0, stream>>>(x, s_wl[0], s_wr[0], s_bl[0],
                                                                     hlb, dvB, N);
    aggr_fused64_bf_k<<<(N + WPB - 1) / WPB, 256, 0, stream>>>(hlb, dvB, rowptr, pairs, hA, N);
    // ---- SAGE layer 1: hA -> hB (64->64), bf16 table
    gemm2_k<64, 64, true><<<(N + 31) / 32, dim3(32, 8), 0, stream>>>(hA, s_wl[1], s_wr[1], s_bl[1],
                                                                     hlb, dvB, N);
    aggr_fused64_bf_k<<<(N + WPB - 1) / WPB, 256, 0, stream>>>(hlb, dvB, rowptr, pairs, hB, N);
    // ---- SAGE layer 2: hB -> hA (64->32), bf16 table, fp32 output
    gemm2_k<64, 32, true><<<(N + 63) / 64, dim3(16, 16), 0, stream>>>(hB, s_wl[2], s_wr[2],
                                                                      s_bl[2], hlb, dvB, N);
    aggr_fused32_bf_k<false><<<(N + WPB - 1) / WPB, 256, 0, stream>>>(hlb, dvB, rowptr, pairs, hA,
                                                                      N);
    // ---- SAGE layer 3: hA -> h3b (32->32), bf16 table, bf16 output
    gemm2_k<32, 32, true><<<(N + 63) / 64, dim3(16, 16), 0, stream>>>(hA, s_wl[3], s_wr[3],
                                                                      s_bl[3], hlb, dvB, N);
    aggr_fused32_bf_k<true><<<(N + WPB - 1) / WPB, 256, 0, stream>>>(hlb, dvB, rowptr, pairs, h3b,
                                                                     N);

    // ---- edge conv chain (fused compute+scatter)
    edge_aggr8_k<<<(N + WPB - 1) / WPB, 256, 0, stream>>>(dis, rowptr, pairs, acc, N);
    hipMemsetAsync(dvA, 0, (size_t)N * 64 * 4, stream);
    edge_compute_scatter_k<8, 64><<<(N + 15) / 16, dim3(64, 4), 0, stream>>>(
        acc, cnt, w12_0, cbuf + 192, cbuf + 192, e_b2[0], cbuf + 0, col, dvA, N);
    hipMemsetAsync(acc, 0, (size_t)N * 64 * 4, stream);
    edge_compute_scatter_k<64, 64><<<(N + 15) / 16, dim3(64, 4), 0, stream>>>(
        dvA, cnt, w12_1, cbuf + 320, cbuf + 256, e_b2[1], cbuf + 64, col, acc, N);
    hipMemsetAsync(dvA, 0, (size_t)N * 32 * 4, stream);
    edge_compute_scatter_k<64, 32><<<(N + 31) / 32, dim3(32, 8), 0, stream>>>(
        acc, cnt, w12_2, cbuf + 416, cbuf + 384, e_b2[2], cbuf + 128, col, dvA, N);
    edge_compute2_k<32, 32><<<(N + 31) / 32, dim3(32, 8), 0, stream>>>(
        dvA, cnt, w12_3, cbuf + 480, cbuf + 448, e_b2[3], dvB, N);

    // ---- final per-edge output (bf16 h3 gathers, 2 edges/thread)
    final_k<<<(E + 511) / 512, 256, 0, stream>>>(h3b, dvB, cbuf + 160, row, col, fcw, fcb,
                                                 (float*)d_out, E, N);
}